// Round 5
// baseline (293.215 us; speedup 1.0000x reference)
//
#include <hip/hip_runtime.h>
#include <math.h>

#define NJ   960      // tail length (global indices 64..1023)
#define NSRC 896      // tail sources (global 128..1023, local 64..959)
#define NWARM 25

// ws layout (floats): Wt[960][64] @ 0 ; base[960] @ 61440
#define WT_F   0u
#define BASE_F (960u * 64u)

// front_k: block 0 runs the ENTIRE warmup on one CU using the separable-
// exponential prefix-scan trick (O(N) per iteration, no cross-block sync).
// Blocks 1..60 compute the Wt head-weight table for batch_k (independent).
__global__ __launch_bounds__(1024) void front_k(const float* __restrict__ ident,
                                                const float* __restrict__ enh,
                                                const float* __restrict__ inh,
                                                const float* __restrict__ beta,
                                                const float* __restrict__ delta,
                                                float* __restrict__ ws) {
  const int tid = threadIdx.x;
  const int lane = tid & 63;
  const int wid = tid >> 6;
  const float bb = beta[0];
  const float dN = delta[0] / 1024.0f;

  if (blockIdx.x > 0) {
    // Wt[j][k] = (d/N) * (e^{-b|E_k - c_{64+j}|} - e^{-b|I_k - c_{64+j}|})
    int j = (blockIdx.x - 1) * 16 + wid;
    float cj = ident[64 + j];
    float e = enh[lane], iv = inh[lane];
    ws[WT_F + j * 64 + lane] =
        dN * (expf(-bb * fabsf(e - cj)) - expf(-bb * fabsf(iv - cj)));
    return;
  }

  // ---------------- block 0: warmup ----------------
  __shared__ float Es[NSRC], Is[NSRC];
  __shared__ float2 bufE[NJ], bufI[NJ];   // scan buffers (rank-ordered)
  __shared__ float4 wsum[16];
  __shared__ float sred[16];
  __shared__ float head_e[64], head_i[64];

  if (tid < NSRC) { Es[tid] = enh[128 + tid]; Is[tid] = inh[128 + tid]; }
  if (tid < 64) { head_e[tid] = enh[tid]; head_i[tid] = inh[tid]; }
  const float cj = (tid < NJ) ? ident[64 + tid] : 0.0f;
  __syncthreads();

  // one-time: source ranks (tid in [64,960) <-> source m = tid-64) and
  // per-column counts (#sources with value <= c_j). All via O(N^2) counting
  // over LDS broadcasts — no sort needed.
  int rE = 0, rI = 0, cntE = 0, cntI = 0;
  {
    const bool issrc = (tid >= 64 && tid < NJ);
    const int sidx = tid - 64;
    const float myE = issrc ? Es[sidx] : 0.0f;
    const float myI = issrc ? Is[sidx] : 0.0f;
    for (int i = 0; i < NSRC; ++i) {
      float ev = Es[i], iv = Is[i];
      if (issrc) {
        rE += (ev < myE || (ev == myE && i < sidx)) ? 1 : 0;
        rI += (iv < myI || (iv == myI && i < sidx)) ? 1 : 0;
      }
      cntE += (ev <= cj) ? 1 : 0;
      cntI += (iv <= cj) ? 1 : 0;
    }
  }

  // per-source exponential transforms (registers)
  float EP = 0, EN = 0, IP = 0, IN = 0;
  if (tid >= 64 && tid < NJ) {
    float e = Es[tid - 64], i2 = Is[tid - 64];
    EP = expf(bb * e); EN = expf(-bb * e);
    IP = expf(bb * i2); IN = expf(-bb * i2);
  }
  // per-column factors + constant head term (head conc = 1/1024, unmasked)
  float fm = 0, fp = 0, hd = 0;
  if (tid < NJ) {
    fm = expf(-bb * cj); fp = expf(bb * cj);
    float h = 0;
    for (int k = 0; k < 64; ++k)
      h += expf(-bb * fabsf(head_e[k] - cj)) - expf(-bb * fabsf(head_i[k] - cj));
    hd = dN * h * (1.0f / 1024.0f);
  }

  const bool sc = (tid < NJ);
  float y = 1.0f / 1024.0f;   // state for column tid

  for (int t = 0; t <= NWARM; ++t) {
    // clear scan buffers (positions 0 and 897..959 stay 0 = shifted prefix)
    if (sc) { bufE[tid] = make_float2(0.f, 0.f); bufI[tid] = make_float2(0.f, 0.f); }
    __syncthreads();
    if (tid >= 64 && tid < NJ) {
      bufE[rE + 1] = make_float2(y * EP, y * EN);
      bufI[rI + 1] = make_float2(y * IP, y * IN);
    }
    __syncthreads();

    // 4-component inclusive block scan over 960 positions (15 full waves)
    float4 x = make_float4(0.f, 0.f, 0.f, 0.f);
    if (sc) {
      float2 a = bufE[tid], b2 = bufI[tid];
      x = make_float4(a.x, a.y, b2.x, b2.y);
    }
    #pragma unroll
    for (int off = 1; off < 64; off <<= 1) {
      float ox = __shfl_up(x.x, off, 64);
      float oy = __shfl_up(x.y, off, 64);
      float oz = __shfl_up(x.z, off, 64);
      float ow = __shfl_up(x.w, off, 64);
      if (lane >= off) { x.x += ox; x.y += oy; x.z += oz; x.w += ow; }
    }
    if (wid < 15 && lane == 63) wsum[wid] = x;
    __syncthreads();
    if (wid == 0) {
      float4 w = (lane < 15) ? wsum[lane] : make_float4(0.f, 0.f, 0.f, 0.f);
      #pragma unroll
      for (int off = 1; off < 16; off <<= 1) {
        float ox = __shfl_up(w.x, off, 64);
        float oy = __shfl_up(w.y, off, 64);
        float oz = __shfl_up(w.z, off, 64);
        float ow = __shfl_up(w.w, off, 64);
        if (lane >= off) { w.x += ox; w.y += oy; w.z += oz; w.w += ow; }
      }
      if (lane < 15) wsum[lane] = w;
    }
    __syncthreads();
    if (sc) {
      if (wid > 0) {
        float4 p = wsum[wid - 1];
        x.x += p.x; x.y += p.y; x.z += p.z; x.w += p.w;
      }
      bufE[tid] = make_float2(x.x, x.y);
      bufI[tid] = make_float2(x.z, x.w);
    }
    __syncthreads();

    // combine: dot_j = fm*prefP(cnt) + fp*(totN - prefN(cnt)), enh - inh
    float newv = 0.0f;
    if (sc) {
      float2 AE = bufE[cntE], AI = bufI[cntI];
      float TNe = bufE[NSRC].y, TNi = bufI[NSRC].y;
      float dot = fm * AE.x + fp * (TNe - AE.y)
                - fm * AI.x - fp * (TNi - AI.y);
      if (t < NWARM) {
        newv = fmaxf(y + dN * dot + hd, 0.0f);
      } else {
        ws[BASE_F + tid] = y + dN * dot;   // batch-step constant (no head)
      }
    }
    if (t < NWARM) {
      // normalization sum over the 960 new values
      float v = newv;
      #pragma unroll
      for (int off = 32; off >= 1; off >>= 1) v += __shfl_xor(v, off);
      if (lane == 0) sred[wid] = v;
      __syncthreads();           // also protects bufE reads vs next clear
      float s = 0.0f;
      #pragma unroll
      for (int w = 0; w < 16; ++w) s += sred[w];
      y = (s > 0.0f) ? newv / s : newv;
    }
  }
}

// Batch step (unchanged structure from round 3, 67 us): one ROW per LANE;
// 16 waves all covering the same 64 rows; wave-uniform W row address ->
// s_load into SGPRs, zero per-lane W traffic.
__global__ __launch_bounds__(1024) void batch_k(const float* __restrict__ inp,
                                                const float* __restrict__ ws,
                                                float* __restrict__ out) {
  __shared__ float ybuf[64 * 65];
  __shared__ float ssbuf[16 * 64];
  __shared__ float invs[64];

  const int tid = threadIdx.x;
  const int lane = tid & 63;
  const int wid = __builtin_amdgcn_readfirstlane(tid >> 6);
  const int row = blockIdx.x * 64 + lane;

  float a[64];
  {
    const float4* ip = (const float4*)(inp + (size_t)row * 64);
    #pragma unroll
    for (int v = 0; v < 16; ++v) {
      float4 t4 = ip[v];
      a[4 * v + 0] = t4.x; a[4 * v + 1] = t4.y;
      a[4 * v + 2] = t4.z; a[4 * v + 3] = t4.w;
    }
  }

  const float* __restrict__ Wt = ws + WT_F;
  const float* __restrict__ base = ws + BASE_F;
  const int j0 = wid * 60;

  float ssum = 0.0f;
  for (int i = 0; i < 60; ++i) {
    const int j = j0 + i;
    const float* __restrict__ wrow = Wt + (size_t)j * 64;
    float d0 = 0.0f, d1 = 0.0f, d2 = 0.0f, d3 = 0.0f;
    #pragma unroll
    for (int k = 0; k < 16; ++k) {
      d0 = fmaf(a[4 * k + 0], wrow[4 * k + 0], d0);
      d1 = fmaf(a[4 * k + 1], wrow[4 * k + 1], d1);
      d2 = fmaf(a[4 * k + 2], wrow[4 * k + 2], d2);
      d3 = fmaf(a[4 * k + 3], wrow[4 * k + 3], d3);
    }
    float yv = fmaxf(((d0 + d1) + (d2 + d3)) + base[j], 0.0f);
    ssum += yv;
    if (j < 64) ybuf[j * 65 + lane] = yv;
  }
  ssbuf[wid * 64 + lane] = ssum;
  __syncthreads();

  if (wid == 0) {
    float t = 0.0f;
    #pragma unroll
    for (int w = 0; w < 16; ++w) t += ssbuf[w * 64 + lane];
    invs[lane] = (t > 0.0f) ? 1.0f / t : 1.0f;
  }
  __syncthreads();

  {
    const int lr = tid >> 4;
    const int c4 = tid & 15;
    const float s = invs[lr];
    float4 o;
    o.x = ybuf[(4 * c4 + 0) * 65 + lr] * s;
    o.y = ybuf[(4 * c4 + 1) * 65 + lr] * s;
    o.z = ybuf[(4 * c4 + 2) * 65 + lr] * s;
    o.w = ybuf[(4 * c4 + 3) * 65 + lr] * s;
    ((float4*)out)[(size_t)blockIdx.x * 1024 + tid] = o;
  }
}

extern "C" void kernel_launch(void* const* d_in, const int* in_sizes, int n_in,
                              void* d_out, int out_size, void* d_ws, size_t ws_size,
                              hipStream_t stream) {
  const float* inp   = (const float*)d_in[0];
  const float* ident = (const float*)d_in[1];
  const float* enh   = (const float*)d_in[2];
  const float* inh   = (const float*)d_in[3];
  const float* beta  = (const float*)d_in[4];
  const float* delta = (const float*)d_in[5];

  hipLaunchKernelGGL(front_k, dim3(61), dim3(1024), 0, stream,
                     ident, enh, inh, beta, delta, (float*)d_ws);
  hipLaunchKernelGGL(batch_k, dim3(256), dim3(1024), 0, stream,
                     inp, (const float*)d_ws, (float*)d_out);
}

// Round 7
// 181.747 us; speedup vs baseline: 1.6133x; 1.6133x over previous
//
#include <hip/hip_runtime.h>
#include <math.h>

#define NJ 960           // tail length (global indices 64..1023)
#define NWARM 25
#define NFB 64           // front blocks
#define NC 15            // columns owned per front block (64*15 = 960)

typedef unsigned long long u64;
typedef unsigned int u32;

// ws layout:
//   Y[2][960] u64 : epoch-tagged y values (tag = iter+1, fp32 low)   @ byte 0
//   P[2][64]  u64 : epoch-tagged per-block partial sums              @ byte 15360
//   Wk[64][960] f32 : head weights TRANSPOSED, (d/N)*S[k][64+j]      @ float 4096
//   base[960]  f32 : batch-step constant                             @ float 65536
#define WK_F   4096u
#define BASE_F (WK_F + 64u * 960u)   // 65536

__device__ __forceinline__ u64 pack_tv(u32 tag, float v) {
  return ((u64)tag << 32) | (u64)__float_as_uint(v);
}
__device__ __forceinline__ void ast(u64* p, u64 v) {
  __hip_atomic_store(p, v, __ATOMIC_RELAXED, __HIP_MEMORY_SCOPE_AGENT);
}
__device__ __forceinline__ u64 ald(const u64* p) {
  return __hip_atomic_load(p, __ATOMIC_RELAXED, __HIP_MEMORY_SCOPE_AGENT);
}

// Dataflow warmup — EXACT round-4 proven structure (88us). Only change:
// head weights are written transposed (Wk[k][j]) for batch_t's coalesced
// staging. 64 blocks, fence-free epoch-tagged atomics.
__global__ __launch_bounds__(1024) void front_k(const float* __restrict__ ident,
                                                const float* __restrict__ enh,
                                                const float* __restrict__ inh,
                                                const float* __restrict__ beta,
                                                const float* __restrict__ delta,
                                                void* __restrict__ wsv) {
  u64* Y = (u64*)wsv;
  u64* P = Y + 2 * NJ;
  float* Wk = (float*)wsv + WK_F;
  float* base = (float*)wsv + BASE_F;

  __shared__ float S2loc[NC * NJ];   // 57.6 KB
  __shared__ float yloc[NJ];
  __shared__ float pvals[NFB];
  __shared__ float psums[NC];
  __shared__ float hdl[NC];

  const int tid = threadIdx.x;
  const int wid = tid >> 6, lane = tid & 63;
  const int b = blockIdx.x;
  const int j0 = b * NC;
  const float bc = beta[0];
  const float dN = delta[0] / 1024.0f;

  if (wid < NC) {
    int j = j0 + wid;
    float cj = ident[64 + j];
    float wv = dN * (expf(-bc * fabsf(enh[lane] - cj)) -
                     expf(-bc * fabsf(inh[lane] - cj)));
    Wk[(size_t)lane * NJ + j] = wv;          // transposed store (one-time)
    float h = wv;
    #pragma unroll
    for (int off = 32; off >= 1; off >>= 1) h += __shfl_xor(h, off);
    if (lane == 0) hdl[wid] = h * (1.0f / 1024.0f);
  }
  for (int idx = tid; idx < NC * NJ; idx += 1024) {
    int c = idx / NJ, m = idx - c * NJ;
    float v = 0.0f;
    if (m >= 64) {
      float cj = ident[64 + j0 + c];
      int g = 64 + m;
      v = dN * (expf(-bc * fabsf(enh[g] - cj)) - expf(-bc * fabsf(inh[g] - cj)));
    }
    S2loc[idx] = v;
  }
  if (tid < NC) ast(&Y[j0 + tid], pack_tv(1u, 1.0f / 1024.0f));
  __syncthreads();

  for (int t = 0; t <= NWARM; ++t) {
    if (tid < NJ) {
      u64* src = &Y[(size_t)(t & 1) * NJ + tid];
      u64 v = ald(src);
      while ((u32)(v >> 32) != (u32)(t + 1)) {
        __builtin_amdgcn_s_sleep(1);
        v = ald(src);
      }
      yloc[tid] = __uint_as_float((u32)v);
    }
    if (t > 0 && tid < NFB) {
      u64* src = &P[(size_t)(t & 1) * NFB + tid];
      u64 v = ald(src);
      while ((u32)(v >> 32) != (u32)(t + 1)) {
        __builtin_amdgcn_s_sleep(1);
        v = ald(src);
      }
      pvals[tid] = __uint_as_float((u32)v);
    }
    __syncthreads();

    float s = 1.0f;
    if (t > 0) {
      float acc = 0.0f;
      #pragma unroll
      for (int i = 0; i < NFB; ++i) acc += pvals[i];
      s = acc;
    }

    if (wid < NC) {
      const float* __restrict__ row = &S2loc[wid * NJ];
      float d = 0.0f;
      #pragma unroll
      for (int i = 0; i < 15; ++i)
        d = fmaf(yloc[lane + 64 * i], row[lane + 64 * i], d);
      #pragma unroll
      for (int off = 32; off >= 1; off >>= 1) d += __shfl_xor(d, off);
      if (lane == 0) {
        float pre = yloc[j0 + wid] + d;
        pre = (s > 0.0f) ? pre / s : pre;
        if (t < NWARM) {
          float yv = fmaxf(pre + hdl[wid], 0.0f);
          psums[wid] = yv;
          ast(&Y[(size_t)((t + 1) & 1) * NJ + j0 + wid],
              pack_tv((u32)(t + 2), yv));
        } else {
          base[j0 + wid] = pre;   // plain store; kernel boundary = sync
        }
      }
    }
    __syncthreads();

    if (t < NWARM && tid < NFB) {
      float pv = (tid < NC) ? psums[tid] : 0.0f;
      #pragma unroll
      for (int off = 32; off >= 1; off >>= 1) pv += __shfl_xor(pv, off);
      if (tid == 0)
        ast(&P[(size_t)((t + 1) & 1) * NFB + b], pack_tv((u32)(t + 2), pv));
    }
  }
}

// Batch step: 256 blocks x 512 threads, 64 rows/block, 8x8 micro-tile
// (FMA:LDS ratio 4.0 = CU balance point). Cols in 2 chunks of 512; the
// OUTPUT chunk (cols 0..511) is processed LAST so output values come from
// still-live acc registers after the row-sum reduction (no y-stash).
// Wave w == row-group w, so row sums reduce with pure shuffles.
// LDS: At 16.9 KB + Wl 33 KB + bch 2 KB ~= 52 KB (< 64 KB limit).
__global__ __launch_bounds__(512) void batch_t(const float* __restrict__ inp,
                                               const float* __restrict__ ws,
                                               float* __restrict__ out) {
  __shared__ float At[64][66];    // A^T: At[k][row]
  __shared__ float Wl[16][516];   // W k-slab: Wl[k%16][col]
  __shared__ float bch[512];

  const int tid = threadIdx.x;
  const int colg = tid & 63;      // 64 col-groups x 8 cols = 512-col chunk
  const int rowg = tid >> 6;      // 8 row-groups x 8 rows; rowg == wave id
  const size_t rowbase = (size_t)blockIdx.x * 64;
  const float* __restrict__ Wk = ws + WK_F;
  const float* __restrict__ base = ws + BASE_F;

  // stage A^T (coalesced read, transposed into LDS)
  #pragma unroll
  for (int i = 0; i < 2; ++i) {
    int fi = tid + i * 512;
    int r = fi >> 4, c4 = (fi & 15) * 4;
    float4 f4 = *(const float4*)(inp + (rowbase + r) * 64 + c4);
    At[c4 + 0][r] = f4.x; At[c4 + 1][r] = f4.y;
    At[c4 + 2][r] = f4.z; At[c4 + 3][r] = f4.w;
  }

  float rs[8];
  #pragma unroll
  for (int r = 0; r < 8; ++r) rs[r] = 0.0f;
  float acc[8][8];

  #pragma unroll 1
  for (int ch = 0; ch < 2; ++ch) {
    const int c0 = ch ? 0 : 512;       // output chunk last
    #pragma unroll
    for (int r = 0; r < 8; ++r)
      #pragma unroll
      for (int c = 0; c < 8; ++c) acc[r][c] = 0.0f;

    __syncthreads();                   // prior bch readers done
    {
      int j = c0 + tid;
      bch[tid] = (j < 960) ? base[j] : -1.0e30f;  // pad cols -> relu 0
    }

    #pragma unroll 1
    for (int s = 0; s < 4; ++s) {      // k-slabs of 16
      __syncthreads();                 // prior Wl readers done (also covers At/bch)
      #pragma unroll
      for (int i = 0; i < 4; ++i) {
        int fi = tid + i * 512;        // 0..2047 float4s
        int kk = fi >> 7;              // 0..15
        int c4 = (fi & 127) * 4;       // 0..508
        int j = c0 + c4;
        float4 v = make_float4(0.f, 0.f, 0.f, 0.f);
        if (j < 960)
          v = *(const float4*)(Wk + (size_t)(16 * s + kk) * NJ + j);
        *(float4*)&Wl[kk][c4] = v;
      }
      __syncthreads();

      #pragma unroll
      for (int kk = 0; kk < 16; ++kk) {
        float4 a0 = *(const float4*)&At[16 * s + kk][rowg * 8];      // broadcast
        float4 a1 = *(const float4*)&At[16 * s + kk][rowg * 8 + 4];
        float4 w0 = *(const float4*)&Wl[kk][colg * 8];
        float4 w1 = *(const float4*)&Wl[kk][colg * 8 + 4];
        float a[8] = {a0.x, a0.y, a0.z, a0.w, a1.x, a1.y, a1.z, a1.w};
        float w[8] = {w0.x, w0.y, w0.z, w0.w, w1.x, w1.y, w1.z, w1.w};
        #pragma unroll
        for (int r = 0; r < 8; ++r)
          #pragma unroll
          for (int c = 0; c < 8; ++c)
            acc[r][c] = fmaf(a[r], w[c], acc[r][c]);
      }
    }

    // fold chunk into row sums
    #pragma unroll
    for (int c = 0; c < 8; ++c) {
      float bv = bch[colg * 8 + c];
      #pragma unroll
      for (int r = 0; r < 8; ++r)
        rs[r] += fmaxf(acc[r][c] + bv, 0.0f);
    }
  }

  // complete row sums across the wave (all 64 lanes share the same 8 rows)
  #pragma unroll
  for (int r = 0; r < 8; ++r) {
    float v = rs[r];
    #pragma unroll
    for (int off = 32; off >= 1; off >>= 1) v += __shfl_xor(v, off);
    rs[r] = v;
  }

  // outputs = cols 0..63 of the LAST chunk -> colg < 8, values from live acc
  if (colg < 8) {
    #pragma unroll
    for (int r = 0; r < 8; ++r) {
      float inv = (rs[r] > 0.0f) ? 1.0f / rs[r] : 1.0f;
      float* op = out + (rowbase + rowg * 8 + r) * 64 + colg * 8;
      float4 o;
      o.x = fmaxf(acc[r][0] + bch[colg * 8 + 0], 0.0f) * inv;
      o.y = fmaxf(acc[r][1] + bch[colg * 8 + 1], 0.0f) * inv;
      o.z = fmaxf(acc[r][2] + bch[colg * 8 + 2], 0.0f) * inv;
      o.w = fmaxf(acc[r][3] + bch[colg * 8 + 3], 0.0f) * inv;
      *(float4*)op = o;
      o.x = fmaxf(acc[r][4] + bch[colg * 8 + 4], 0.0f) * inv;
      o.y = fmaxf(acc[r][5] + bch[colg * 8 + 5], 0.0f) * inv;
      o.z = fmaxf(acc[r][6] + bch[colg * 8 + 6], 0.0f) * inv;
      o.w = fmaxf(acc[r][7] + bch[colg * 8 + 7], 0.0f) * inv;
      *(float4*)(op + 4) = o;
    }
  }
}

extern "C" void kernel_launch(void* const* d_in, const int* in_sizes, int n_in,
                              void* d_out, int out_size, void* d_ws, size_t ws_size,
                              hipStream_t stream) {
  const float* inp   = (const float*)d_in[0];
  const float* ident = (const float*)d_in[1];
  const float* enh   = (const float*)d_in[2];
  const float* inh   = (const float*)d_in[3];
  const float* beta  = (const float*)d_in[4];
  const float* delta = (const float*)d_in[5];

  hipLaunchKernelGGL(front_k, dim3(NFB), dim3(1024), 0, stream,
                     ident, enh, inh, beta, delta, d_ws);
  hipLaunchKernelGGL(batch_t, dim3(256), dim3(512), 0, stream,
                     inp, (const float*)d_ws, (float*)d_out);
}

// Round 8
// 158.809 us; speedup vs baseline: 1.8463x; 1.1444x over previous
//
#include <hip/hip_runtime.h>
#include <math.h>

#define NJ 960           // tail columns (global 64..1023)
#define NSRC 896         // tail sources (global 128..1023) = local cols 64..959
#define NWARM 25

typedef unsigned long long u64;
typedef unsigned int u32;

// ws layout:
//   RK[896] u64 : tag | (rE | rI<<16)        @ u64 idx 0
//   CT[960] u64 : tag | (cntE | cntI<<16)    @ u64 idx 896
//   HD[960] u64 : tag | float bits of hd[j]  @ u64 idx 1856
//   Wk[64][960] f32 (transposed head weights) @ float idx 8192
//   base[960] f32                             @ float idx 69632
#define RK_O   0u
#define CT_O   896u
#define HD_O   1856u
#define WK_F   8192u
#define BASE_F (WK_F + 64u * 960u)

#define TAG_RK 0x524B0001u
#define TAG_CT 0x43540001u
#define TAG_HD 0x48440001u

__device__ __forceinline__ void ast(u64* p, u64 v) {
  __hip_atomic_store(p, v, __ATOMIC_RELAXED, __HIP_MEMORY_SCOPE_AGENT);
}
__device__ __forceinline__ u64 ald(const u64* p) {
  return __hip_atomic_load(p, __ATOMIC_RELAXED, __HIP_MEMORY_SCOPE_AGENT);
}
__device__ __forceinline__ u32 poll32(const u64* p, u32 tag) {
  u64 v = ald(p);
  while ((u32)(v >> 32) != tag) { __builtin_amdgcn_s_sleep(1); v = ald(p); }
  return (u32)v;
}

// front_k: block 0 = single-block scan warmup (4 waves). blocks 1..30 = prep
// (ranks/counts/hd via 8-lane groups + Wk table), publishing via epoch tags.
__global__ __launch_bounds__(256) void front_k(const float* __restrict__ ident,
                                               const float* __restrict__ enh,
                                               const float* __restrict__ inh,
                                               const float* __restrict__ beta,
                                               const float* __restrict__ delta,
                                               void* __restrict__ wsv) {
  u64* RK = (u64*)wsv + RK_O;
  u64* CT = (u64*)wsv + CT_O;
  u64* HD = (u64*)wsv + HD_O;
  float* Wk = (float*)wsv + WK_F;
  float* base = (float*)wsv + BASE_F;

  const int tid = threadIdx.x;
  const float bb = beta[0];
  const float dN = delta[0] / 1024.0f;

  if (blockIdx.x > 0) {
    // ---------------- prep blocks ----------------
    const int g = (blockIdx.x - 1) * 256 + tid;   // 0..7679
    const int c8 = g & 7;                          // 8-lane chunk id
    // A: source ranks (g < 7168): source m = g>>3, chunk over 112 sources
    if (g < NSRC * 8) {
      int m = g >> 3;
      float myE = enh[128 + m], myI = inh[128 + m];
      int re = 0, ri = 0;
      for (int i = 112 * c8; i < 112 * c8 + 112; ++i) {
        float ev = enh[128 + i], iv = inh[128 + i];
        re += (ev < myE || (ev == myE && i < m)) ? 1 : 0;
        ri += (iv < myI || (iv == myI && i < m)) ? 1 : 0;
      }
      int p = re | (ri << 16);
      p += __shfl_xor(p, 1); p += __shfl_xor(p, 2); p += __shfl_xor(p, 4);
      if (c8 == 0) ast(&RK[m], ((u64)TAG_RK << 32) | (u32)p);
    }
    // B: per-column counts (all 7680): col j = g>>3
    {
      int j = g >> 3;
      float cj = ident[64 + j];
      int ce = 0, ci = 0;
      for (int i = 112 * c8; i < 112 * c8 + 112; ++i) {
        ce += (enh[128 + i] <= cj) ? 1 : 0;
        ci += (inh[128 + i] <= cj) ? 1 : 0;
      }
      int p = ce | (ci << 16);
      p += __shfl_xor(p, 1); p += __shfl_xor(p, 2); p += __shfl_xor(p, 4);
      if (c8 == 0) ast(&CT[j], ((u64)TAG_CT << 32) | (u32)p);
    }
    // C: head constants hd[j]
    {
      int j = g >> 3;
      float cj = ident[64 + j];
      float h = 0.0f;
      for (int k = 8 * c8; k < 8 * c8 + 8; ++k)
        h += expf(-bb * fabsf(enh[k] - cj)) - expf(-bb * fabsf(inh[k] - cj));
      h += __shfl_xor(h, 1); h += __shfl_xor(h, 2); h += __shfl_xor(h, 4);
      if (c8 == 0)
        ast(&HD[j], ((u64)TAG_HD << 32) |
                    (u64)__float_as_uint(dN * h * (1.0f / 1024.0f)));
    }
    // D: Wk table (transposed): k = g/120, cols jb..jb+7
    {
      int k = g / 120;
      int jb = (g % 120) * 8;
      float ek = enh[k], ik = inh[k];
      #pragma unroll
      for (int u = 0; u < 8; ++u) {
        float cj = ident[64 + jb + u];
        Wk[(size_t)k * NJ + jb + u] =
            dN * (expf(-bb * fabsf(ek - cj)) - expf(-bb * fabsf(ik - cj)));
      }
    }
    return;
  }

  // ---------------- block 0: scan warmup ----------------
  __shared__ float yl[NJ];
  __shared__ float2 scanE[1024];
  __shared__ float2 scanI[1024];
  __shared__ float4 wtot[4];
  __shared__ float ssw[4];

  const int lane = tid & 63, wvid = tid >> 6;

  // poll prep results
  int rE[4], rI[4];
  if (tid < 224) {
    #pragma unroll
    for (int s = 0; s < 4; ++s) {
      u32 v = poll32(&RK[4 * tid + s], TAG_RK);
      rE[s] = v & 0xFFFF; rI[s] = v >> 16;
    }
  }
  int cE[4], cI[4];
  float hd[4], fm[4], fp[4];
  if (tid < 240) {
    #pragma unroll
    for (int c = 0; c < 4; ++c) {
      u32 v = poll32(&CT[4 * tid + c], TAG_CT);
      cE[c] = v & 0xFFFF; cI[c] = v >> 16;
      hd[c] = __uint_as_float(poll32(&HD[4 * tid + c], TAG_HD));
      float cj = ident[64 + 4 * tid + c];
      fm[c] = expf(-bb * cj); fp[c] = expf(bb * cj);
    }
  }
  // local source transforms
  float EP[4], EN[4], IP[4], IN2[4];
  if (tid < 224) {
    #pragma unroll
    for (int s = 0; s < 4; ++s) {
      float e = enh[128 + 4 * tid + s], i2 = inh[128 + 4 * tid + s];
      EP[s] = expf(bb * e);  EN[s] = expf(-bb * e);
      IP[s] = expf(bb * i2); IN2[s] = expf(-bb * i2);
    }
  }
  float y_own[4] = {1.0f / 1024.0f, 1.0f / 1024.0f, 1.0f / 1024.0f, 1.0f / 1024.0f};
  if (tid < 240) {
    #pragma unroll
    for (int c = 0; c < 4; ++c) yl[4 * tid + c] = 1.0f / 1024.0f;
  }
  __syncthreads();

  for (int t = 0; t <= NWARM; ++t) {
    // S: zeros (pos 0 and 897..1023) + scatter by rank
    if (tid == 0) {
      scanE[0] = make_float2(0.f, 0.f);
      scanI[0] = make_float2(0.f, 0.f);
    }
    if (tid >= 224) {
      #pragma unroll
      for (int c = 0; c < 4; ++c) {
        int p = 4 * tid + c;
        if (p > NSRC) {
          scanE[p] = make_float2(0.f, 0.f);
          scanI[p] = make_float2(0.f, 0.f);
        }
      }
    }
    if (tid < 224) {
      #pragma unroll
      for (int s = 0; s < 4; ++s) {
        float ym = yl[64 + 4 * tid + s];
        scanE[rE[s] + 1] = make_float2(ym * EP[s], ym * EN[s]);
        scanI[rI[s] + 1] = make_float2(ym * IP[s], ym * IN2[s]);
      }
    }
    __syncthreads();

    // P: local prefix (4 positions) + wave scan of totals
    float2 e0 = scanE[4 * tid], e1 = scanE[4 * tid + 1],
           e2 = scanE[4 * tid + 2], e3 = scanE[4 * tid + 3];
    float2 i0 = scanI[4 * tid], i1 = scanI[4 * tid + 1],
           i2v = scanI[4 * tid + 2], i3 = scanI[4 * tid + 3];
    e1.x += e0.x; e1.y += e0.y; e2.x += e1.x; e2.y += e1.y; e3.x += e2.x; e3.y += e2.y;
    i1.x += i0.x; i1.y += i0.y; i2v.x += i1.x; i2v.y += i1.y; i3.x += i2v.x; i3.y += i2v.y;
    float4 tot = make_float4(e3.x, e3.y, i3.x, i3.y);
    float4 inc = tot;
    #pragma unroll
    for (int off = 1; off < 64; off <<= 1) {
      float ox = __shfl_up(inc.x, off, 64);
      float oy = __shfl_up(inc.y, off, 64);
      float oz = __shfl_up(inc.z, off, 64);
      float ow = __shfl_up(inc.w, off, 64);
      if (lane >= off) { inc.x += ox; inc.y += oy; inc.z += oz; inc.w += ow; }
    }
    if (lane == 63) wtot[wvid] = inc;
    __syncthreads();
    float4 exc = make_float4(inc.x - tot.x, inc.y - tot.y,
                             inc.z - tot.z, inc.w - tot.w);
    #pragma unroll
    for (int w = 0; w < 3; ++w)
      if (w < wvid) {
        float4 p = wtot[w];
        exc.x += p.x; exc.y += p.y; exc.z += p.z; exc.w += p.w;
      }
    e0.x += exc.x; e0.y += exc.y; e1.x += exc.x; e1.y += exc.y;
    e2.x += exc.x; e2.y += exc.y; e3.x += exc.x; e3.y += exc.y;
    i0.x += exc.z; i0.y += exc.w; i1.x += exc.z; i1.y += exc.w;
    i2v.x += exc.z; i2v.y += exc.w; i3.x += exc.z; i3.y += exc.w;
    scanE[4 * tid] = e0; scanE[4 * tid + 1] = e1;
    scanE[4 * tid + 2] = e2; scanE[4 * tid + 3] = e3;
    scanI[4 * tid] = i0; scanI[4 * tid + 1] = i1;
    scanI[4 * tid + 2] = i2v; scanI[4 * tid + 3] = i3;
    __syncthreads();

    // C: combine at precomputed counts
    float nv[4] = {0.f, 0.f, 0.f, 0.f};
    float psum = 0.0f;
    if (tid < 240) {
      float2 TE = scanE[NSRC], TI = scanI[NSRC];
      #pragma unroll
      for (int c = 0; c < 4; ++c) {
        float2 AE = scanE[cE[c]], AI = scanI[cI[c]];
        float dot = fm[c] * AE.x + fp[c] * (TE.y - AE.y)
                  - fm[c] * AI.x - fp[c] * (TI.y - AI.y);
        float pre = y_own[c] + dN * dot;
        if (t < NWARM) {
          nv[c] = fmaxf(pre + hd[c], 0.0f);
          psum += nv[c];
        } else {
          base[4 * tid + c] = pre;
        }
      }
    }
    if (t < NWARM) {
      #pragma unroll
      for (int off = 32; off >= 1; off >>= 1) psum += __shfl_xor(psum, off);
      if (lane == 0) ssw[wvid] = psum;
      __syncthreads();
      float s = ssw[0] + ssw[1] + ssw[2] + ssw[3];
      float inv = (s > 0.0f) ? 1.0f / s : 1.0f;
      if (tid < 240) {
        #pragma unroll
        for (int c = 0; c < 4; ++c) {
          y_own[c] = nv[c] * inv;
          yl[4 * tid + c] = y_own[c];
        }
      }
    }
    __syncthreads();   // yl stable; scan bufs free for next scatter
  }
}

// Batch step (round-7 proven): 256 blocks x 512 threads, 64 rows/block,
// 8x8 micro-tile; output chunk processed last -> values from live acc.
__global__ __launch_bounds__(512) void batch_t(const float* __restrict__ inp,
                                               const float* __restrict__ ws,
                                               float* __restrict__ out) {
  __shared__ float At[64][66];
  __shared__ float Wl[16][516];
  __shared__ float bch[512];

  const int tid = threadIdx.x;
  const int colg = tid & 63;
  const int rowg = tid >> 6;
  const size_t rowbase = (size_t)blockIdx.x * 64;
  const float* __restrict__ Wk = ws + WK_F;
  const float* __restrict__ base = ws + BASE_F;

  #pragma unroll
  for (int i = 0; i < 2; ++i) {
    int fi = tid + i * 512;
    int r = fi >> 4, c4 = (fi & 15) * 4;
    float4 f4 = *(const float4*)(inp + (rowbase + r) * 64 + c4);
    At[c4 + 0][r] = f4.x; At[c4 + 1][r] = f4.y;
    At[c4 + 2][r] = f4.z; At[c4 + 3][r] = f4.w;
  }

  float rs[8];
  #pragma unroll
  for (int r = 0; r < 8; ++r) rs[r] = 0.0f;
  float acc[8][8];

  #pragma unroll 1
  for (int ch = 0; ch < 2; ++ch) {
    const int c0 = ch ? 0 : 512;
    #pragma unroll
    for (int r = 0; r < 8; ++r)
      #pragma unroll
      for (int c = 0; c < 8; ++c) acc[r][c] = 0.0f;

    __syncthreads();
    {
      int j = c0 + tid;
      bch[tid] = (j < 960) ? base[j] : -1.0e30f;
    }

    #pragma unroll 1
    for (int s = 0; s < 4; ++s) {
      __syncthreads();
      #pragma unroll
      for (int i = 0; i < 4; ++i) {
        int fi = tid + i * 512;
        int kk = fi >> 7;
        int c4 = (fi & 127) * 4;
        int j = c0 + c4;
        float4 v = make_float4(0.f, 0.f, 0.f, 0.f);
        if (j < 960)
          v = *(const float4*)(Wk + (size_t)(16 * s + kk) * NJ + j);
        *(float4*)&Wl[kk][c4] = v;
      }
      __syncthreads();

      #pragma unroll
      for (int kk = 0; kk < 16; ++kk) {
        float4 a0 = *(const float4*)&At[16 * s + kk][rowg * 8];
        float4 a1 = *(const float4*)&At[16 * s + kk][rowg * 8 + 4];
        float4 w0 = *(const float4*)&Wl[kk][colg * 8];
        float4 w1 = *(const float4*)&Wl[kk][colg * 8 + 4];
        float a[8] = {a0.x, a0.y, a0.z, a0.w, a1.x, a1.y, a1.z, a1.w};
        float w[8] = {w0.x, w0.y, w0.z, w0.w, w1.x, w1.y, w1.z, w1.w};
        #pragma unroll
        for (int r = 0; r < 8; ++r)
          #pragma unroll
          for (int c = 0; c < 8; ++c)
            acc[r][c] = fmaf(a[r], w[c], acc[r][c]);
      }
    }

    #pragma unroll
    for (int c = 0; c < 8; ++c) {
      float bv = bch[colg * 8 + c];
      #pragma unroll
      for (int r = 0; r < 8; ++r)
        rs[r] += fmaxf(acc[r][c] + bv, 0.0f);
    }
  }

  #pragma unroll
  for (int r = 0; r < 8; ++r) {
    float v = rs[r];
    #pragma unroll
    for (int off = 32; off >= 1; off >>= 1) v += __shfl_xor(v, off);
    rs[r] = v;
  }

  if (colg < 8) {
    #pragma unroll
    for (int r = 0; r < 8; ++r) {
      float inv = (rs[r] > 0.0f) ? 1.0f / rs[r] : 1.0f;
      float* op = out + (rowbase + rowg * 8 + r) * 64 + colg * 8;
      float4 o;
      o.x = fmaxf(acc[r][0] + bch[colg * 8 + 0], 0.0f) * inv;
      o.y = fmaxf(acc[r][1] + bch[colg * 8 + 1], 0.0f) * inv;
      o.z = fmaxf(acc[r][2] + bch[colg * 8 + 2], 0.0f) * inv;
      o.w = fmaxf(acc[r][3] + bch[colg * 8 + 3], 0.0f) * inv;
      *(float4*)op = o;
      o.x = fmaxf(acc[r][4] + bch[colg * 8 + 4], 0.0f) * inv;
      o.y = fmaxf(acc[r][5] + bch[colg * 8 + 5], 0.0f) * inv;
      o.z = fmaxf(acc[r][6] + bch[colg * 8 + 6], 0.0f) * inv;
      o.w = fmaxf(acc[r][7] + bch[colg * 8 + 7], 0.0f) * inv;
      *(float4*)(op + 4) = o;
    }
  }
}

extern "C" void kernel_launch(void* const* d_in, const int* in_sizes, int n_in,
                              void* d_out, int out_size, void* d_ws, size_t ws_size,
                              hipStream_t stream) {
  const float* inp   = (const float*)d_in[0];
  const float* ident = (const float*)d_in[1];
  const float* enh   = (const float*)d_in[2];
  const float* inh   = (const float*)d_in[3];
  const float* beta  = (const float*)d_in[4];
  const float* delta = (const float*)d_in[5];

  hipLaunchKernelGGL(front_k, dim3(31), dim3(256), 0, stream,
                     ident, enh, inh, beta, delta, d_ws);
  hipLaunchKernelGGL(batch_t, dim3(256), dim3(512), 0, stream,
                     inp, (const float*)d_ws, (float*)d_out);
}